// Round 4
// baseline (101.255 us; speedup 1.0000x reference)
//
#include <hip/hip_runtime.h>

#define N_NODES 256
#define F_DIM   16
#define H_DIM   2048
#define P_DIM   16
#define E_EDGES 32768
#define BLK     512
#define NW      (BLK / 64)

typedef float f32x4 __attribute__((ext_vector_type(4)));  // native vector: OK for nontemporal builtins

// ---------------------------------------------------------------------------
// Single fused kernel, zero workspace. Algebra (re-associated GCN):
//   g[n][f] = dinv[n] * sum_s (cnt[n][s] + [s==n]) * dinv[s] * x[s][f]
//   o[n][h] = sum_f g[n][f] W[f][h] + b[h]
//   q[n][p] = sum_h o[n][h] Wq[n][h][p] + bq[n][p],  dinv = rsqrt(indeg+1)
// Block n rebuilds the full degree histogram + its own count row from the raw
// edge list (L2-resident, per-wave LDS histograms), fully overlapped with the
// irreducible 128 KB/block Wq HBM stream. Wq is pre-issued nontemporally at
// kernel entry (zero reuse -> don't evict the edge list from L2). Mid-section
// trimmed to 2 syncs: dinv folded into g-phase registers, gfin LDS roundtrip
// replaced by 4-way gw broadcast reads.
// ---------------------------------------------------------------------------
__global__ __launch_bounds__(BLK) void k_fused(
    const int* __restrict__ ei,   const float* __restrict__ x,
    const float* __restrict__ W,  const float* __restrict__ b,
    const float* __restrict__ Wq, const float* __restrict__ bq,
    float* __restrict__ qout)
{
    __shared__ unsigned histw[NW][N_NODES];   // per-wave degree histograms
    __shared__ unsigned cntrow[N_NODES];      // cnt[n][s] for this block's n
    __shared__ float    dinv[N_NODES];
    __shared__ float    gw[4][F_DIM];
    __shared__ float    red[NW][P_DIM];

    const int n = blockIdx.x;
    const int t = threadIdx.x;
    const int w = t >> 6, l = t & 63;

    // ---- pre-issue the entire Wq stream (16 float4/thread, nontemporal).
    // Lands during the edge scan; consumed only at the ACC stage.
    const f32x4* Wqn = (const f32x4*)(Wq + (size_t)n * (H_DIM * P_DIM));
    f32x4 u[16];
#pragma unroll
    for (int k = 0; k < 16; ++k)
        u[k] = __builtin_nontemporal_load(&Wqn[(t + ((k >> 2) * BLK)) * 4 + (k & 3)]);

    // ---- zero LDS histograms (2048 + 256 words over 512 threads)
#pragma unroll
    for (int i = 0; i < 4; ++i) ((unsigned*)histw)[t + i * BLK] = 0u;
    if (t < N_NODES) cntrow[t] = 0u;
    __syncthreads();

    // ---- edge scan: 4 edges/thread/iter, int4 coalesced, L2-resident.
    // unroll 4 keeps in-flight edge VGPRs modest next to the held u[16].
#pragma unroll 4
    for (int k = 0; k < 16; ++k) {
        const int base = (k << 11) + (t << 2);          // k*2048 + t*4
        int4 s4 = *(const int4*)(ei + base);
        int4 d4 = *(const int4*)(ei + E_EDGES + base);
        atomicAdd(&histw[w][d4.x], 1u);
        atomicAdd(&histw[w][d4.y], 1u);
        atomicAdd(&histw[w][d4.z], 1u);
        atomicAdd(&histw[w][d4.w], 1u);
        if (d4.x == n) atomicAdd(&cntrow[s4.x], 1u);
        if (d4.y == n) atomicAdd(&cntrow[s4.y], 1u);
        if (d4.z == n) atomicAdd(&cntrow[s4.z], 1u);
        if (d4.w == n) atomicAdd(&cntrow[s4.w], 1u);
    }
    __syncthreads();

    // ---- g-phase with fused dinv: thread t owns source s=t.
    if (t < N_NODES) {
        unsigned dg = 0;
#pragma unroll
        for (int i = 0; i < NW; ++i) dg += histw[i][t];
        float dt = rsqrtf((float)dg + 1.0f);
        dinv[t] = dt;                                   // only dinv[n] is reused
        float a = ((float)cntrow[t] + (t == n ? 1.0f : 0.0f)) * dt;
        const float4* x4 = (const float4*)(x + t * F_DIM);
        float4 a0 = x4[0], a1 = x4[1], a2 = x4[2], a3 = x4[3];
        float val[F_DIM];
        val[0]  = a * a0.x; val[1]  = a * a0.y; val[2]  = a * a0.z; val[3]  = a * a0.w;
        val[4]  = a * a1.x; val[5]  = a * a1.y; val[6]  = a * a1.z; val[7]  = a * a1.w;
        val[8]  = a * a2.x; val[9]  = a * a2.y; val[10] = a * a2.z; val[11] = a * a2.w;
        val[12] = a * a3.x; val[13] = a * a3.y; val[14] = a * a3.z; val[15] = a * a3.w;
#pragma unroll
        for (int f = 0; f < F_DIM; ++f)
#pragma unroll
            for (int off = 32; off > 0; off >>= 1)
                val[f] += __shfl_xor(val[f], off, 64);
        if (l == 0) {
#pragma unroll
            for (int f = 0; f < F_DIM; ++f) gw[w][f] = val[f];
        }
    }
    __syncthreads();

    // ---- gr: 4-way cross-wave combine via LDS broadcast (no extra sync)
    const float dn = dinv[n];
    float gr[F_DIM];
#pragma unroll
    for (int f = 0; f < F_DIM; ++f)
        gr[f] = (gw[0][f] + gw[1][f] + gw[2][f] + gw[3][f]) * dn;

    // ---- o[i] = b[hh] + sum_f gr[f]*W[f][hh], hh = t + 512*i (coalesced L2)
    float o[4];
#pragma unroll
    for (int i = 0; i < 4; ++i) {
        int hh = t + BLK * i;
        float v = b[hh];
#pragma unroll
        for (int f = 0; f < F_DIM; ++f)
            v += gr[f] * W[f * H_DIM + hh];
        o[i] = v;
    }

    // ---- acc[p] += o * Wq (u registers landed during the edge scan)
    float acc[16];
#pragma unroll
    for (int p = 0; p < 16; ++p) acc[p] = 0.0f;

#define ACC4(OV, U0, U1, U2, U3) { float ov = (OV);                            \
    acc[0]  += ov * U0.x; acc[1]  += ov * U0.y; acc[2]  += ov * U0.z; acc[3]  += ov * U0.w; \
    acc[4]  += ov * U1.x; acc[5]  += ov * U1.y; acc[6]  += ov * U1.z; acc[7]  += ov * U1.w; \
    acc[8]  += ov * U2.x; acc[9]  += ov * U2.y; acc[10] += ov * U2.z; acc[11] += ov * U2.w; \
    acc[12] += ov * U3.x; acc[13] += ov * U3.y; acc[14] += ov * U3.z; acc[15] += ov * U3.w; }

    ACC4(o[0], u[0],  u[1],  u[2],  u[3])
    ACC4(o[1], u[4],  u[5],  u[6],  u[7])
    ACC4(o[2], u[8],  u[9],  u[10], u[11])
    ACC4(o[3], u[12], u[13], u[14], u[15])
#undef ACC4

    // ---- wave butterfly then cross-wave via LDS
#pragma unroll
    for (int p = 0; p < 16; ++p)
#pragma unroll
        for (int off = 32; off > 0; off >>= 1)
            acc[p] += __shfl_down(acc[p], off, 64);

    if (l == 0) {
#pragma unroll
        for (int p = 0; p < 16; ++p) red[w][p] = acc[p];
    }
    __syncthreads();
    if (t < P_DIM) {
        float s = bq[n * P_DIM + t];
#pragma unroll
        for (int ww = 0; ww < NW; ++ww) s += red[ww][t];
        qout[n * P_DIM + t] = s;
    }
}

extern "C" void kernel_launch(void* const* d_in, const int* in_sizes, int n_in,
                              void* d_out, int out_size, void* d_ws, size_t ws_size,
                              hipStream_t stream) {
    const float* x  = (const float*)d_in[0];  // [256,16]
    const int*   ei = (const int*)d_in[1];    // [2,32768]
    const float* W  = (const float*)d_in[2];  // [16,2048]
    const float* b  = (const float*)d_in[3];  // [2048]
    const float* Wq = (const float*)d_in[4];  // [256,2048,16]
    const float* bq = (const float*)d_in[5];  // [256,16]
    float* qout = (float*)d_out;              // [256,16]

    (void)d_ws; (void)ws_size;                // workspace unused: single launch
    k_fused<<<N_NODES, BLK, 0, stream>>>(ei, x, W, b, Wq, bq, qout);
}

// Round 5
// 91.763 us; speedup vs baseline: 1.1034x; 1.1034x over previous
//
#include <hip/hip_runtime.h>

#define N_NODES 256
#define F_DIM   16
#define H_DIM   2048
#define P_DIM   16
#define E_EDGES 32768
#define BLK     512
#define NW      (BLK / 64)

// ---------------------------------------------------------------------------
// Single fused kernel, zero workspace. Algebra (re-associated GCN):
//   g[n][f] = dinv[n] * sum_s (cnt[n][s] + [s==n]) * dinv[s] * x[s][f]
//   o[n][h] = sum_f g[n][f] W[f][h] + b[h]
//   q[n][p] = sum_h o[n][h] Wq[n][h][p] + bq[n][p],  dinv = rsqrt(indeg+1)
//
// Pipeline (vmcnt-FIFO-aware: a consume waits for its own load, draining all
// OLDER loads — so streams meant to overlap must be issued YOUNGER):
//   issue edges[0..7] -> issue Wq[0..7] -> zero LDS -> consume edges[0..7]
//   issue edges[8..15] -> issue Wq[8..15] -> consume edges[8..15]
//   (Wq[8..15] additionally hides under g-phase + W-matvec)
// R4's bug: Wq issued OLDEST serialized the whole 128 KB stream before the
// first atomic. nt loads dropped (unproven, possible L3-hit forfeiture).
// ---------------------------------------------------------------------------
__global__ __launch_bounds__(BLK) void k_fused(
    const int* __restrict__ ei,   const float* __restrict__ x,
    const float* __restrict__ W,  const float* __restrict__ b,
    const float* __restrict__ Wq, const float* __restrict__ bq,
    float* __restrict__ qout)
{
    __shared__ unsigned histw[NW][N_NODES];   // per-wave degree histograms
    __shared__ unsigned cntrow[N_NODES];      // cnt[n][s] for this block's n
    __shared__ float    dinv[N_NODES];
    __shared__ float    gw[4][F_DIM];
    __shared__ float    red[NW][P_DIM];

    const int n = blockIdx.x;
    const int t = threadIdx.x;
    const int w = t >> 6, l = t & 63;

    const float4* Wqn = (const float4*)(Wq + (size_t)n * (H_DIM * P_DIM));

    // ---- stage A issue: edges[0..7] first (oldest), then Wq[0..7] (younger,
    // stays outstanding through the edge-consume waits below).
    int4 s4[8], d4[8];
#pragma unroll
    for (int k = 0; k < 8; ++k) {
        const int base = (k << 11) + (t << 2);          // k*2048 + t*4
        s4[k] = *(const int4*)(ei + base);
        d4[k] = *(const int4*)(ei + E_EDGES + base);
    }
    float4 u[16];
#pragma unroll
    for (int k = 0; k < 8; ++k)
        u[k] = Wqn[(t + ((k >> 2) * BLK)) * 4 + (k & 3)];

    // ---- zero LDS histograms (2048 + 256 words over 512 threads); ds_writes
    // and barrier don't touch vmcnt — loads stay in flight across this.
#pragma unroll
    for (int i = 0; i < 4; ++i) ((unsigned*)histw)[t + i * BLK] = 0u;
    if (t < N_NODES) cntrow[t] = 0u;
    __syncthreads();

    // ---- stage A consume: ~28 LDS atomics/thread of latency cover for Wq[0..7]
#pragma unroll
    for (int k = 0; k < 8; ++k) {
        atomicAdd(&histw[w][d4[k].x], 1u);
        atomicAdd(&histw[w][d4[k].y], 1u);
        atomicAdd(&histw[w][d4[k].z], 1u);
        atomicAdd(&histw[w][d4[k].w], 1u);
        if (d4[k].x == n) atomicAdd(&cntrow[s4[k].x], 1u);
        if (d4[k].y == n) atomicAdd(&cntrow[s4[k].y], 1u);
        if (d4[k].z == n) atomicAdd(&cntrow[s4[k].z], 1u);
        if (d4[k].w == n) atomicAdd(&cntrow[s4[k].w], 1u);
    }

    // ---- stage B issue: edges[8..15], then Wq[8..15] (covered by stage B
    // consume + g-phase + W-matvec before first use in ACC).
#pragma unroll
    for (int k = 0; k < 8; ++k) {
        const int base = ((k + 8) << 11) + (t << 2);
        s4[k] = *(const int4*)(ei + base);
        d4[k] = *(const int4*)(ei + E_EDGES + base);
    }
#pragma unroll
    for (int k = 8; k < 16; ++k)
        u[k] = Wqn[(t + ((k >> 2) * BLK)) * 4 + (k & 3)];

    // ---- stage B consume
#pragma unroll
    for (int k = 0; k < 8; ++k) {
        atomicAdd(&histw[w][d4[k].x], 1u);
        atomicAdd(&histw[w][d4[k].y], 1u);
        atomicAdd(&histw[w][d4[k].z], 1u);
        atomicAdd(&histw[w][d4[k].w], 1u);
        if (d4[k].x == n) atomicAdd(&cntrow[s4[k].x], 1u);
        if (d4[k].y == n) atomicAdd(&cntrow[s4[k].y], 1u);
        if (d4[k].z == n) atomicAdd(&cntrow[s4[k].z], 1u);
        if (d4[k].w == n) atomicAdd(&cntrow[s4[k].w], 1u);
    }
    __syncthreads();

    // ---- g-phase with fused dinv: thread t owns source s=t.
    if (t < N_NODES) {
        unsigned dg = 0;
#pragma unroll
        for (int i = 0; i < NW; ++i) dg += histw[i][t];
        float dt = rsqrtf((float)dg + 1.0f);
        dinv[t] = dt;                                   // only dinv[n] is reused
        float a = ((float)cntrow[t] + (t == n ? 1.0f : 0.0f)) * dt;
        const float4* x4 = (const float4*)(x + t * F_DIM);
        float4 a0 = x4[0], a1 = x4[1], a2 = x4[2], a3 = x4[3];
        float val[F_DIM];
        val[0]  = a * a0.x; val[1]  = a * a0.y; val[2]  = a * a0.z; val[3]  = a * a0.w;
        val[4]  = a * a1.x; val[5]  = a * a1.y; val[6]  = a * a1.z; val[7]  = a * a1.w;
        val[8]  = a * a2.x; val[9]  = a * a2.y; val[10] = a * a2.z; val[11] = a * a2.w;
        val[12] = a * a3.x; val[13] = a * a3.y; val[14] = a * a3.z; val[15] = a * a3.w;
#pragma unroll
        for (int f = 0; f < F_DIM; ++f)
#pragma unroll
            for (int off = 32; off > 0; off >>= 1)
                val[f] += __shfl_xor(val[f], off, 64);
        if (l == 0) {
#pragma unroll
            for (int f = 0; f < F_DIM; ++f) gw[w][f] = val[f];
        }
    }
    __syncthreads();

    // ---- gr: 4-way cross-wave combine via LDS broadcast (no extra sync)
    const float dn = dinv[n];
    float gr[F_DIM];
#pragma unroll
    for (int f = 0; f < F_DIM; ++f)
        gr[f] = (gw[0][f] + gw[1][f] + gw[2][f] + gw[3][f]) * dn;

    // ---- o[i] = b[hh] + sum_f gr[f]*W[f][hh], hh = t + 512*i (coalesced L2)
    float o[4];
#pragma unroll
    for (int i = 0; i < 4; ++i) {
        int hh = t + BLK * i;
        float v = b[hh];
#pragma unroll
        for (int f = 0; f < F_DIM; ++f)
            v += gr[f] * W[f * H_DIM + hh];
        o[i] = v;
    }

    // ---- acc[p] += o * Wq (u registers landed during the edge scan / matvec)
    float acc[16];
#pragma unroll
    for (int p = 0; p < 16; ++p) acc[p] = 0.0f;

#define ACC4(OV, U0, U1, U2, U3) { float ov = (OV);                            \
    acc[0]  += ov * U0.x; acc[1]  += ov * U0.y; acc[2]  += ov * U0.z; acc[3]  += ov * U0.w; \
    acc[4]  += ov * U1.x; acc[5]  += ov * U1.y; acc[6]  += ov * U1.z; acc[7]  += ov * U1.w; \
    acc[8]  += ov * U2.x; acc[9]  += ov * U2.y; acc[10] += ov * U2.z; acc[11] += ov * U2.w; \
    acc[12] += ov * U3.x; acc[13] += ov * U3.y; acc[14] += ov * U3.z; acc[15] += ov * U3.w; }

    ACC4(o[0], u[0],  u[1],  u[2],  u[3])
    ACC4(o[1], u[4],  u[5],  u[6],  u[7])
    ACC4(o[2], u[8],  u[9],  u[10], u[11])
    ACC4(o[3], u[12], u[13], u[14], u[15])
#undef ACC4

    // ---- wave butterfly then cross-wave via LDS
#pragma unroll
    for (int p = 0; p < 16; ++p)
#pragma unroll
        for (int off = 32; off > 0; off >>= 1)
            acc[p] += __shfl_down(acc[p], off, 64);

    if (l == 0) {
#pragma unroll
        for (int p = 0; p < 16; ++p) red[w][p] = acc[p];
    }
    __syncthreads();
    if (t < P_DIM) {
        float s = bq[n * P_DIM + t];
#pragma unroll
        for (int ww = 0; ww < NW; ++ww) s += red[ww][t];
        qout[n * P_DIM + t] = s;
    }
}

extern "C" void kernel_launch(void* const* d_in, const int* in_sizes, int n_in,
                              void* d_out, int out_size, void* d_ws, size_t ws_size,
                              hipStream_t stream) {
    const float* x  = (const float*)d_in[0];  // [256,16]
    const int*   ei = (const int*)d_in[1];    // [2,32768]
    const float* W  = (const float*)d_in[2];  // [16,2048]
    const float* b  = (const float*)d_in[3];  // [2048]
    const float* Wq = (const float*)d_in[4];  // [256,2048,16]
    const float* bq = (const float*)d_in[5];  // [256,16]
    float* qout = (float*)d_out;              // [256,16]

    (void)d_ws; (void)ws_size;                // workspace unused: single launch
    k_fused<<<N_NODES, BLK, 0, stream>>>(ei, x, W, b, Wq, bq, qout);
}